// Round 1
// baseline (265.658 us; speedup 1.0000x reference)
//
#include <hip/hip_runtime.h>

// OctreeDWConv: out[i,c] = sum_k (neigh[i,k]>=0 ? data[neigh[i,k],c] : 0) * w[k,c]
// N=200000, K=27, C=64, fp32 in/out.
//
// Layout: 16 lanes per row (each lane owns 4 channels as float4), so every
// gather of data[n, :] is one contiguous 256B segment -> coalesced 16B/lane.
// Wave = 4 rows, block(256) = 16 rows, grid = N/16 = 12500 blocks exactly.

constexpr int K  = 27;
constexpr int C  = 64;
constexpr int C4 = C / 4;            // 16 float4 per row
constexpr int ROWS_PER_BLOCK = 16;   // 256 threads / 16 lanes-per-row

__global__ __launch_bounds__(256) void octree_dwconv_kernel(
    const float* __restrict__ data,
    const float* __restrict__ weights,
    const int*   __restrict__ neigh,
    float*       __restrict__ out,
    int nrows)
{
    __shared__ float4 w_lds[K * C4];   // 27 * 16 float4 = 6912 B

    const int tid = threadIdx.x;
    // Stage weights into LDS once per block (432 float4, 2 iters of 256).
    for (int idx = tid; idx < K * C4; idx += 256) {
        w_lds[idx] = reinterpret_cast<const float4*>(weights)[idx];
    }
    __syncthreads();

    const int l     = tid & (C4 - 1);     // lane-in-group: channels 4l..4l+3
    const int group = tid >> 4;           // 0..15: row within block
    const int row   = blockIdx.x * ROWS_PER_BLOCK + group;
    if (row >= nrows) return;

    const int* __restrict__ nrow = neigh + row * K;

    // Preload all 27 neighbor indices -> 27 loads in flight up front.
    int nk[K];
    #pragma unroll
    for (int k = 0; k < K; ++k) nk[k] = nrow[k];

    const float4* __restrict__ data4 = reinterpret_cast<const float4*>(data);
    float4 acc = make_float4(0.f, 0.f, 0.f, 0.f);

    #pragma unroll
    for (int k = 0; k < K; ++k) {
        const int n    = nk[k];
        const int safe = (n < 0) ? 0 : n;            // clamp -> always load
        float4 d = data4[safe * C4 + l];             // 256B/group gather
        const float4 w = w_lds[k * C4 + l];
        if (n < 0) d = make_float4(0.f, 0.f, 0.f, 0.f);  // v_cndmask x4
        acc.x = fmaf(d.x, w.x, acc.x);
        acc.y = fmaf(d.y, w.y, acc.y);
        acc.z = fmaf(d.z, w.z, acc.z);
        acc.w = fmaf(d.w, w.w, acc.w);
    }

    reinterpret_cast<float4*>(out)[row * C4 + l] = acc;  // coalesced 16B/lane
}

extern "C" void kernel_launch(void* const* d_in, const int* in_sizes, int n_in,
                              void* d_out, int out_size, void* d_ws, size_t ws_size,
                              hipStream_t stream) {
    const float* data    = (const float*)d_in[0];   // [N, C] fp32
    const float* weights = (const float*)d_in[1];   // [K, 1, C] fp32
    const int*   neigh   = (const int*)d_in[2];     // [N, K] int32
    float*       out     = (float*)d_out;           // [N, C] fp32

    const int nrows  = in_sizes[0] / C;             // 200000
    const int blocks = (nrows + ROWS_PER_BLOCK - 1) / ROWS_PER_BLOCK;

    octree_dwconv_kernel<<<blocks, 256, 0, stream>>>(data, weights, neigh, out, nrows);
}